// Round 1
// baseline (888.982 us; speedup 1.0000x reference)
//
#include <hip/hip_runtime.h>
#include <math.h>

#define D 128
#define B2D 256
#define NSEG 64

// ---------------- init / copy ----------------
__global__ void k_zero(float* p, int n) {
    int i = blockIdx.x * blockDim.x + threadIdx.x;
    if (i < n) p[i] = 0.f;
}

__global__ void k_copy(const float* __restrict__ s, float* __restrict__ d, int n) {
    int i = blockIdx.x * blockDim.x + threadIdx.x;
    if (i < n) d[i] = s[i];
}

// ---------------- segment offsets (edge_batch is sorted) ----------------
__global__ void k_ofs(const int* __restrict__ eb, int* __restrict__ seg_ofs, int E) {
    int e = blockIdx.x * blockDim.x + threadIdx.x;
    if (e >= E) return;
    int b = eb[e];
    if (e == 0) {
        for (int j = 0; j <= b; ++j) seg_ofs[j] = 0;
    } else {
        int p = eb[e - 1];
        if (p != b) for (int j = p + 1; j <= b; ++j) seg_ofs[j] = e;
    }
    if (e == E - 1) {
        for (int j = b + 1; j <= NSEG; ++j) seg_ofs[j] = E;
    }
}

// ---------------- LSTM cell: one block per batch row ----------------
__global__ __launch_bounds__(512) void k_lstm(
        const float* __restrict__ w_ih, const float* __restrict__ w_hh,
        const float* __restrict__ b_ih, const float* __restrict__ b_hh,
        float* __restrict__ h, float* __restrict__ c, float* __restrict__ q_star) {
    int b = blockIdx.x;   // 0..63
    int t = threadIdx.x;  // 0..511  (gate index, order i|f|g|o)
    __shared__ float s_x[B2D];
    __shared__ float s_h[D];
    __shared__ float s_g[4 * D];
    if (t < B2D) s_x[t] = q_star[b * B2D + t];
    else if (t < B2D + D) s_h[t - B2D] = h[b * D + (t - B2D)];
    __syncthreads();

    float acc = b_ih[t] + b_hh[t];
    const float* wr = w_ih + (size_t)t * B2D;
    #pragma unroll 8
    for (int k = 0; k < B2D; k += 4) {
        float4 w4 = *(const float4*)(wr + k);
        acc += w4.x * s_x[k] + w4.y * s_x[k + 1] + w4.z * s_x[k + 2] + w4.w * s_x[k + 3];
    }
    const float* wh = w_hh + (size_t)t * D;
    #pragma unroll 8
    for (int k = 0; k < D; k += 4) {
        float4 w4 = *(const float4*)(wh + k);
        acc += w4.x * s_h[k] + w4.y * s_h[k + 1] + w4.z * s_h[k + 2] + w4.w * s_h[k + 3];
    }
    s_g[t] = acc;
    __syncthreads();

    if (t < D) {
        float gi = s_g[t], gf = s_g[t + D], gg = s_g[t + 2 * D], go = s_g[t + 3 * D];
        float si = 1.f / (1.f + expf(-gi));
        float sf = 1.f / (1.f + expf(-gf));
        float so = 1.f / (1.f + expf(-go));
        float cn = sf * c[b * D + t] + si * tanhf(gg);
        float hn = so * tanhf(cn);
        c[b * D + t] = cn;
        h[b * D + t] = hn;
        q_star[b * B2D + t] = hn;            // q half
        q_star[b * B2D + D + t] = 0.f;       // zero readout slot for atomics
    }
}

// ---------------- per-edge logits: e[e] = feat[e] . q[batch[e]] ----------------
// Each half-wave (32 lanes, float4 each = one 512B row) handles one edge.
__global__ __launch_bounds__(256) void k_logits(
        const float* __restrict__ feat, const int* __restrict__ eb,
        const float* __restrict__ h, float* __restrict__ e_arr, int E, int cpw) {
    int wave = (blockIdx.x * blockDim.x + threadIdx.x) >> 6;
    int lane = threadIdx.x & 63;
    int half = lane >> 5;
    int sl = lane & 31;
    long e0 = (long)wave * cpw;
    long eend = e0 + cpw; if (eend > E) eend = E;
    if (e0 >= E) return;

    int cur_b = -1;
    float4 q4 = make_float4(0.f, 0.f, 0.f, 0.f);
    for (long e = e0; e < eend; e += 2) {
        long my_e = e + half;
        float partial = 0.f;
        if (my_e < eend) {
            int b = eb[my_e];
            if (b != cur_b) {
                cur_b = b;
                q4 = *(const float4*)(h + (size_t)b * D + sl * 4);
            }
            float4 f4 = *(const float4*)(feat + (size_t)my_e * D + sl * 4);
            partial = f4.x * q4.x + f4.y * q4.y + f4.z * q4.z + f4.w * q4.w;
        }
        partial += __shfl_down(partial, 16, 32);
        partial += __shfl_down(partial, 8, 32);
        partial += __shfl_down(partial, 4, 32);
        partial += __shfl_down(partial, 2, 32);
        partial += __shfl_down(partial, 1, 32);
        if (sl == 0 && my_e < eend) e_arr[my_e] = partial;
    }
}

// ---------------- per-segment softmax stats (one block per segment) ----------------
__global__ __launch_bounds__(256) void k_stats(
        const float* __restrict__ e_arr, const int* __restrict__ seg_ofs,
        float* __restrict__ e_max, float* __restrict__ e_sum) {
    int b = blockIdx.x;
    int s = seg_ofs[b], t = seg_ofs[b + 1];
    __shared__ float red[256];
    float m = -INFINITY;
    for (int e = s + threadIdx.x; e < t; e += 256) m = fmaxf(m, e_arr[e]);
    red[threadIdx.x] = m;
    __syncthreads();
    for (int ofs = 128; ofs > 0; ofs >>= 1) {
        if (threadIdx.x < ofs) red[threadIdx.x] = fmaxf(red[threadIdx.x], red[threadIdx.x + ofs]);
        __syncthreads();
    }
    m = red[0];
    __syncthreads();
    float sum = 0.f;
    for (int e = s + threadIdx.x; e < t; e += 256) sum += expf(e_arr[e] - m);
    red[threadIdx.x] = sum;
    __syncthreads();
    for (int ofs = 128; ofs > 0; ofs >>= 1) {
        if (threadIdx.x < ofs) red[threadIdx.x] += red[threadIdx.x + ofs];
        __syncthreads();
    }
    if (threadIdx.x == 0) { e_max[b] = m; e_sum[b] = red[0]; }
}

// ---------------- weighted readout: q_star[b][128+d] += feat[e][d]*alpha[e] ----------------
__global__ __launch_bounds__(256) void k_readout(
        const float* __restrict__ feat, const int* __restrict__ eb,
        const float* __restrict__ e_arr, const float* __restrict__ e_max,
        const float* __restrict__ e_sum, float* __restrict__ q_star, int E, int cpw) {
    int wave = (blockIdx.x * blockDim.x + threadIdx.x) >> 6;
    int lane = threadIdx.x & 63;
    int half = lane >> 5;
    int sl = lane & 31;
    long e0 = (long)wave * cpw;
    long eend = e0 + cpw; if (eend > E) eend = E;
    if (e0 >= E) return;

    int cur_b = -1;
    float em = 0.f, es = 1.f;
    float4 acc = make_float4(0.f, 0.f, 0.f, 0.f);
    for (long e = e0; e < eend; e += 2) {
        long my_e = e + half;
        if (my_e < eend) {
            int b = eb[my_e];
            if (b != cur_b) {
                if (cur_b >= 0) {
                    float* dst = q_star + (size_t)cur_b * B2D + D + sl * 4;
                    atomicAdd(dst + 0, acc.x);
                    atomicAdd(dst + 1, acc.y);
                    atomicAdd(dst + 2, acc.z);
                    atomicAdd(dst + 3, acc.w);
                    acc = make_float4(0.f, 0.f, 0.f, 0.f);
                }
                cur_b = b;
                em = e_max[b];
                es = e_sum[b] + 1e-8f;
            }
            float alpha = expf(e_arr[my_e] - em) / es;
            float4 f4 = *(const float4*)(feat + (size_t)my_e * D + sl * 4);
            acc.x += f4.x * alpha;
            acc.y += f4.y * alpha;
            acc.z += f4.z * alpha;
            acc.w += f4.w * alpha;
        }
    }
    if (cur_b >= 0) {
        float* dst = q_star + (size_t)cur_b * B2D + D + sl * 4;
        atomicAdd(dst + 0, acc.x);
        atomicAdd(dst + 1, acc.y);
        atomicAdd(dst + 2, acc.z);
        atomicAdd(dst + 3, acc.w);
    }
}

extern "C" void kernel_launch(void* const* d_in, const int* in_sizes, int n_in,
                              void* d_out, int out_size, void* d_ws, size_t ws_size,
                              hipStream_t stream) {
    const float* feat = (const float*)d_in[0];
    const int*   eb   = (const int*)d_in[1];
    const float* w_ih = (const float*)d_in[2];
    const float* w_hh = (const float*)d_in[3];
    const float* b_ih = (const float*)d_in[4];
    const float* b_hh = (const float*)d_in[5];
    float* out = (float*)d_out;
    float* ws  = (float*)d_ws;
    const int E = in_sizes[1];   // 500000

    // workspace layout (floats)
    float* h      = ws;                 // 64*128
    float* c      = ws + 8192;          // 64*128
    float* q_star = ws + 16384;         // 64*256
    float* e_max  = ws + 32768;         // 64
    float* e_sum  = ws + 32832;         // 64
    int*   seg    = (int*)(ws + 32896); // 65 ints
    float* e_arr  = ws + 33024;         // E floats

    // zero LSTM state + q_star
    k_zero<<<128, 256, 0, stream>>>(ws, 32768);
    // segment offsets (once per call; input is sorted)
    k_ofs<<<(E + 255) / 256, 256, 0, stream>>>(eb, seg, E);

    const int BLOCKS = 2048, THREADS = 256;
    const int waves = BLOCKS * THREADS / 64;           // 8192
    const int cpw = (E + waves - 1) / waves;           // 62 edges per wave

    for (int it = 0; it < 3; ++it) {
        k_lstm<<<NSEG, 512, 0, stream>>>(w_ih, w_hh, b_ih, b_hh, h, c, q_star);
        k_logits<<<BLOCKS, THREADS, 0, stream>>>(feat, eb, h, e_arr, E, cpw);
        k_stats<<<NSEG, 256, 0, stream>>>(e_arr, seg, e_max, e_sum);
        k_readout<<<BLOCKS, THREADS, 0, stream>>>(feat, eb, e_arr, e_max, e_sum, q_star, E, cpw);
    }
    k_copy<<<64, 256, 0, stream>>>(q_star, out, out_size);
}

// Round 2
// 561.128 us; speedup vs baseline: 1.5843x; 1.5843x over previous
//
#include <hip/hip_runtime.h>
#include <math.h>

#define D 128
#define B2D 256
#define NSEG 64
#define MAXC 512
#define PSTRIDE 144   // floats per chunk-partial: [0]=m, [1]=s, [8..135]=acc[128]

// ---------------- init / copy ----------------
__global__ void k_zero(float* p, int n) {
    int i = blockIdx.x * blockDim.x + threadIdx.x;
    if (i < n) p[i] = 0.f;
}

__global__ void k_copy(const float* __restrict__ s, float* __restrict__ d, int n) {
    int i = blockIdx.x * blockDim.x + threadIdx.x;
    if (i < n) d[i] = s[i];
}

// ---------------- segment offsets (edge_batch is sorted) ----------------
__global__ void k_ofs(const int* __restrict__ eb, int* __restrict__ seg_ofs, int E) {
    int e = blockIdx.x * blockDim.x + threadIdx.x;
    if (e >= E) return;
    int b = eb[e];
    if (e == 0) {
        for (int j = 0; j <= b; ++j) seg_ofs[j] = 0;
    } else {
        int p = eb[e - 1];
        if (p != b) for (int j = p + 1; j <= b; ++j) seg_ofs[j] = e;
    }
    if (e == E - 1) {
        for (int j = b + 1; j <= NSEG; ++j) seg_ofs[j] = E;
    }
}

// ---------------- per-segment chunking: chunk counts, prefix, edges-per-wave ----------------
__global__ void k_seginfo(const int* __restrict__ seg_ofs, int* __restrict__ pre,
                          int* __restrict__ epw) {
    __shared__ int cnt[NSEG];
    int b = threadIdx.x;
    if (b < NSEG) {
        int len = seg_ofs[b + 1] - seg_ofs[b];
        int e = 62;
        int c = (len + e - 1) / e;
        if (c > MAXC) { e = (len + MAXC - 1) / MAXC; c = (len + e - 1) / e; }
        if (len == 0) c = 0;
        epw[b] = e;
        cnt[b] = c;
    }
    __syncthreads();
    if (threadIdx.x == 0) {
        int acc = 0;
        for (int j = 0; j < NSEG; ++j) { pre[j] = acc; acc += cnt[j]; }
        pre[NSEG] = acc;
    }
}

// ---------------- LSTM cell: one block per batch row ----------------
__global__ __launch_bounds__(512) void k_lstm(
        const float* __restrict__ w_ih, const float* __restrict__ w_hh,
        const float* __restrict__ b_ih, const float* __restrict__ b_hh,
        float* __restrict__ h, float* __restrict__ c, float* __restrict__ q_star) {
    int b = blockIdx.x;   // 0..63
    int t = threadIdx.x;  // 0..511  (gate index, order i|f|g|o)
    __shared__ float s_x[B2D];
    __shared__ float s_h[D];
    __shared__ float s_g[4 * D];
    if (t < B2D) s_x[t] = q_star[b * B2D + t];
    else if (t < B2D + D) s_h[t - B2D] = h[b * D + (t - B2D)];
    __syncthreads();

    float acc = b_ih[t] + b_hh[t];
    const float* wr = w_ih + (size_t)t * B2D;
    #pragma unroll 8
    for (int k = 0; k < B2D; k += 4) {
        float4 w4 = *(const float4*)(wr + k);
        acc += w4.x * s_x[k] + w4.y * s_x[k + 1] + w4.z * s_x[k + 2] + w4.w * s_x[k + 3];
    }
    const float* wh = w_hh + (size_t)t * D;
    #pragma unroll 8
    for (int k = 0; k < D; k += 4) {
        float4 w4 = *(const float4*)(wh + k);
        acc += w4.x * s_h[k] + w4.y * s_h[k + 1] + w4.z * s_h[k + 2] + w4.w * s_h[k + 3];
    }
    s_g[t] = acc;
    __syncthreads();

    if (t < D) {
        float gi = s_g[t], gf = s_g[t + D], gg = s_g[t + 2 * D], go = s_g[t + 3 * D];
        float si = 1.f / (1.f + expf(-gi));
        float sf = 1.f / (1.f + expf(-gf));
        float so = 1.f / (1.f + expf(-go));
        float cn = sf * c[b * D + t] + si * tanhf(gg);
        float hn = so * tanhf(cn);
        c[b * D + t] = cn;
        h[b * D + t] = hn;
        q_star[b * B2D + t] = hn;            // q half
    }
}

// ---------------- fused single-pass: logits + online softmax + weighted accumulate ----------------
// One wave per chunk; chunks never cross segment boundaries. Each half-wave
// (32 lanes x float4 = one 512B feat row) handles one edge per step.
__global__ __launch_bounds__(256) void k_pass(
        const float* __restrict__ feat, const int* __restrict__ seg_ofs,
        const int* __restrict__ pre, const int* __restrict__ epw,
        const float* __restrict__ h, float* __restrict__ part) {
    __shared__ int s_pre[NSEG + 1], s_ofs[NSEG + 1], s_epw[NSEG];
    int tid = threadIdx.x;
    if (tid <= NSEG) { s_pre[tid] = pre[tid]; s_ofs[tid] = seg_ofs[tid]; }
    if (tid < NSEG) s_epw[tid] = epw[tid];
    __syncthreads();
    int total = s_pre[NSEG];
    int wave = (blockIdx.x * blockDim.x + tid) >> 6;
    int nwaves = (gridDim.x * blockDim.x) >> 6;
    int lane = tid & 63, half = lane >> 5, sl = lane & 31;

    for (int cid = wave; cid < total; cid += nwaves) {
        // binary search: largest b with s_pre[b] <= cid
        int lo = 0, hi = NSEG - 1;
        while (lo < hi) {
            int mid = (lo + hi + 1) >> 1;
            if (s_pre[mid] <= cid) lo = mid; else hi = mid - 1;
        }
        int b = lo;
        int chunk = cid - s_pre[b];
        int e = s_epw[b];
        long s0 = (long)s_ofs[b] + (long)chunk * e;
        long s1 = (long)s_ofs[b + 1];
        long send = s0 + e;
        if (send < s1) s1 = send;

        float4 q4 = *(const float4*)(h + (size_t)b * D + sl * 4);
        float m = -INFINITY, ssum = 0.f;
        float4 acc = make_float4(0.f, 0.f, 0.f, 0.f);

        for (long ee = s0; ee < s1; ee += 2) {
            long my_e = ee + half;
            bool valid = my_e < s1;
            float4 f4 = make_float4(0.f, 0.f, 0.f, 0.f);
            if (valid) f4 = *(const float4*)(feat + (size_t)my_e * D + sl * 4);
            float p = f4.x * q4.x + f4.y * q4.y + f4.z * q4.z + f4.w * q4.w;
            p += __shfl_xor(p, 16, 32);
            p += __shfl_xor(p, 8, 32);
            p += __shfl_xor(p, 4, 32);
            p += __shfl_xor(p, 2, 32);
            p += __shfl_xor(p, 1, 32);   // all 32 lanes now hold the full logit
            if (valid) {
                float nm = fmaxf(m, p);
                float sc = __expf(m - nm);   // exp(-inf)=0 handles first edge
                float we = __expf(p - nm);
                ssum = ssum * sc + we;
                acc.x = acc.x * sc + we * f4.x;
                acc.y = acc.y * sc + we * f4.y;
                acc.z = acc.z * sc + we * f4.z;
                acc.w = acc.w * sc + we * f4.w;
                m = nm;
            }
        }
        // merge the two half-wave states
        float m_o = __shfl_xor(m, 32);
        float s_o = __shfl_xor(ssum, 32);
        float4 a_o;
        a_o.x = __shfl_xor(acc.x, 32);
        a_o.y = __shfl_xor(acc.y, 32);
        a_o.z = __shfl_xor(acc.z, 32);
        a_o.w = __shfl_xor(acc.w, 32);
        float nm = fmaxf(m, m_o);            // at least one half saw an edge
        float sa = __expf(m - nm), sb = __expf(m_o - nm);
        float sm = ssum * sa + s_o * sb;
        float4 am;
        am.x = acc.x * sa + a_o.x * sb;
        am.y = acc.y * sa + a_o.y * sb;
        am.z = acc.z * sa + a_o.z * sb;
        am.w = acc.w * sa + a_o.w * sb;

        float* dst = part + (size_t)cid * PSTRIDE;
        if (lane == 0) { dst[0] = nm; dst[1] = sm; }
        if (half == 0) *(float4*)(dst + 8 + sl * 4) = am;
    }
}

// ---------------- combine chunk partials per segment (no atomics) ----------------
__global__ __launch_bounds__(128) void k_combine(
        const float* __restrict__ part, const int* __restrict__ pre,
        float* __restrict__ q_star) {
    int b = blockIdx.x, t = threadIdx.x;
    int c0 = pre[b], c1 = pre[b + 1];
    int nc = c1 - c0;
    __shared__ float s_w[MAXC];
    __shared__ float red[128];

    // pass 1: global max of chunk maxima
    float M = -INFINITY;
    for (int c = t; c < nc; c += 128) M = fmaxf(M, part[(size_t)(c0 + c) * PSTRIDE]);
    red[t] = M; __syncthreads();
    for (int o = 64; o > 0; o >>= 1) {
        if (t < o) red[t] = fmaxf(red[t], red[t + o]);
        __syncthreads();
    }
    M = red[0]; __syncthreads();

    // pass 2: per-chunk weights + rescaled sum
    float S = 0.f;
    for (int c = t; c < nc; c += 128) {
        const float* pe = part + (size_t)(c0 + c) * PSTRIDE;
        float w = __expf(pe[0] - M);
        s_w[c] = w;
        S += w * pe[1];
    }
    red[t] = S; __syncthreads();
    for (int o = 64; o > 0; o >>= 1) {
        if (t < o) red[t] += red[t + o];
        __syncthreads();
    }
    S = red[0]; __syncthreads();

    // pass 3: rescaled accumulator, one feature dim per thread
    float R = 0.f;
    for (int c = 0; c < nc; ++c)
        R += s_w[c] * part[(size_t)(c0 + c) * PSTRIDE + 8 + t];
    q_star[b * B2D + D + t] = R / (S + 1e-8f);
}

extern "C" void kernel_launch(void* const* d_in, const int* in_sizes, int n_in,
                              void* d_out, int out_size, void* d_ws, size_t ws_size,
                              hipStream_t stream) {
    const float* feat = (const float*)d_in[0];
    const int*   eb   = (const int*)d_in[1];
    const float* w_ih = (const float*)d_in[2];
    const float* w_hh = (const float*)d_in[3];
    const float* b_ih = (const float*)d_in[4];
    const float* b_hh = (const float*)d_in[5];
    float* out = (float*)d_out;
    float* ws  = (float*)d_ws;
    const int E = in_sizes[1];   // 500000

    // workspace layout (float offsets)
    float* h      = ws;                  // 64*128
    float* c      = ws + 8192;           // 64*128
    float* q_star = ws + 16384;          // 64*256
    int*   seg    = (int*)(ws + 32768);  // 65
    int*   pre    = (int*)(ws + 32840);  // 65
    int*   epw    = (int*)(ws + 32912);  // 64
    float* part   = ws + 33024;          // up to 64*512*144 floats (~19 MB)

    // zero LSTM state + q_star
    k_zero<<<128, 256, 0, stream>>>(ws, 32768);
    // segment offsets (input is sorted) + chunk mapping
    k_ofs<<<(E + 255) / 256, 256, 0, stream>>>(eb, seg, E);
    k_seginfo<<<1, 64, 0, stream>>>(seg, pre, epw);

    const int BLOCKS = 2048, THREADS = 256;  // 8192 waves, full device residency
    for (int it = 0; it < 3; ++it) {
        k_lstm<<<NSEG, 512, 0, stream>>>(w_ih, w_hh, b_ih, b_hh, h, c, q_star);
        k_pass<<<BLOCKS, THREADS, 0, stream>>>(feat, seg, pre, epw, h, part);
        k_combine<<<NSEG, 128, 0, stream>>>(part, pre, q_star);
    }
    k_copy<<<64, 256, 0, stream>>>(q_star, out, out_size);
}